// Round 5
// baseline (425.492 us; speedup 1.0000x reference)
//
#include <hip/hip_runtime.h>
#include <math.h>

// ---------------------------------------------------------------------------
// ManifoldNet SPD network, fused in log-domain.
// logm(x) once -> 10 convs (zero-pad fused into staging) on the 6 unique
// components of the symmetric log field (treated as batch) -> expm once.
// Conv v5: weights staged in LDS (broadcast ds_read_b128, 4 co at a time),
// wave-level co/y split, P=4 pixels per thread. Inner loop = LDS + FMA only.
// ---------------------------------------------------------------------------

#define DEVFN __device__ __forceinline__

DEVFN void jrot(float A[3][3], float V[3][3], int p, int q) {
    float apq = A[p][q];
    if (fabsf(apq) < 1e-30f) return;
    float app = A[p][p], aqq = A[q][q];
    float tau = (aqq - app) / (2.0f * apq);
    float t = copysignf(1.0f, tau) / (fabsf(tau) + sqrtf(1.0f + tau * tau));
    float c = rsqrtf(1.0f + t * t);
    float s = t * c;
    int r = 3 - p - q;
    float arp = A[r][p], arq = A[r][q];
    A[p][p] = app - t * apq;
    A[q][q] = aqq + t * apq;
    A[p][q] = 0.0f; A[q][p] = 0.0f;
    A[r][p] = c * arp - s * arq; A[p][r] = A[r][p];
    A[r][q] = s * arp + c * arq; A[q][r] = A[r][q];
#pragma unroll
    for (int i = 0; i < 3; ++i) {
        float vip = V[i][p], viq = V[i][q];
        V[i][p] = c * vip - s * viq;
        V[i][q] = s * vip + c * viq;
    }
}

DEVFN void eigh3(float A[3][3], float V[3][3]) {
    V[0][0] = 1.f; V[0][1] = 0.f; V[0][2] = 0.f;
    V[1][0] = 0.f; V[1][1] = 1.f; V[1][2] = 0.f;
    V[2][0] = 0.f; V[2][1] = 0.f; V[2][2] = 1.f;
#pragma unroll
    for (int s = 0; s < 6; ++s) {
        jrot(A, V, 0, 1);
        jrot(A, V, 0, 2);
        jrot(A, V, 1, 2);
    }
}

// x: [n,3,3] SPD (f32). out: planar [6][n], comps (00,01,02,11,12,22).
__global__ void logm_k(const float* __restrict__ x, float* __restrict__ out, int n) {
    int i = blockIdx.x * blockDim.x + threadIdx.x;
    if (i >= n) return;
    const float* m = x + (size_t)i * 9;
    float a01 = 0.5f * (m[1] + m[3]);
    float a02 = 0.5f * (m[2] + m[6]);
    float a12 = 0.5f * (m[5] + m[7]);
    float A[3][3] = {{m[0], a01, a02}, {a01, m[4], a12}, {a02, a12, m[8]}};
    float V[3][3];
    eigh3(A, V);
    float d0 = logf(fmaxf(A[0][0], 1e-30f));
    float d1 = logf(fmaxf(A[1][1], 1e-30f));
    float d2 = logf(fmaxf(A[2][2], 1e-30f));
    float L00 = V[0][0]*d0*V[0][0] + V[0][1]*d1*V[0][1] + V[0][2]*d2*V[0][2];
    float L01 = V[0][0]*d0*V[1][0] + V[0][1]*d1*V[1][1] + V[0][2]*d2*V[1][2];
    float L02 = V[0][0]*d0*V[2][0] + V[0][1]*d1*V[2][1] + V[0][2]*d2*V[2][2];
    float L11 = V[1][0]*d0*V[1][0] + V[1][1]*d1*V[1][1] + V[1][2]*d2*V[1][2];
    float L12 = V[1][0]*d0*V[2][0] + V[1][1]*d1*V[2][1] + V[1][2]*d2*V[2][2];
    float L22 = V[2][0]*d0*V[2][0] + V[2][1]*d1*V[2][1] + V[2][2]*d2*V[2][2];
    out[0 * (size_t)n + i] = L00;
    out[1 * (size_t)n + i] = L01;
    out[2 * (size_t)n + i] = L02;
    out[3 * (size_t)n + i] = L11;
    out[4 * (size_t)n + i] = L12;
    out[5 * (size_t)n + i] = L22;
}

__global__ void expm_k(const float* __restrict__ Lp, float* __restrict__ out, int n) {
    int i = blockIdx.x * blockDim.x + threadIdx.x;
    if (i >= n) return;
    float a00 = Lp[0 * (size_t)n + i];
    float a01 = Lp[1 * (size_t)n + i];
    float a02 = Lp[2 * (size_t)n + i];
    float a11 = Lp[3 * (size_t)n + i];
    float a12 = Lp[4 * (size_t)n + i];
    float a22 = Lp[5 * (size_t)n + i];
    float A[3][3] = {{a00, a01, a02}, {a01, a11, a12}, {a02, a12, a22}};
    float V[3][3];
    eigh3(A, V);
    float e0 = expf(A[0][0]);
    float e1 = expf(A[1][1]);
    float e2 = expf(A[2][2]);
    float m00 = V[0][0]*e0*V[0][0] + V[0][1]*e1*V[0][1] + V[0][2]*e2*V[0][2];
    float m01 = V[0][0]*e0*V[1][0] + V[0][1]*e1*V[1][1] + V[0][2]*e2*V[1][2];
    float m02 = V[0][0]*e0*V[2][0] + V[0][1]*e1*V[2][1] + V[0][2]*e2*V[2][2];
    float m11 = V[1][0]*e0*V[1][0] + V[1][1]*e1*V[1][1] + V[1][2]*e2*V[1][2];
    float m12 = V[1][0]*e0*V[2][0] + V[1][1]*e1*V[2][1] + V[1][2]*e2*V[2][2];
    float m22 = V[2][0]*e0*V[2][0] + V[2][1]*e1*V[2][1] + V[2][2]*e2*V[2][2];
    float* o = out + (size_t)i * 9;
    o[0] = m00; o[1] = m01; o[2] = m02;
    o[3] = m01; o[4] = m11; o[5] = m12;
    o[6] = m02; o[7] = m12; o[8] = m22;
}

// One kernel for all 10 layer softmaxes: block l = layer l, thread co.
struct WP {
    const float* src[10];
    float* dst[10];
    int Co[10];
    int n[10];
};
__global__ void softmax_all(WP wp) {
    int l = blockIdx.x;
    int co = threadIdx.x;
    if (co >= wp.Co[l]) return;
    int n = wp.n[l];
    const float* src = wp.src[l] + (size_t)co * n;
    float* dst = wp.dst[l] + (size_t)co * n;
    float mx = -1e30f;
    for (int i = 0; i < n; ++i) mx = fmaxf(mx, src[i]);
    float s = 0.f;
    for (int i = 0; i < n; ++i) s += expf(src[i] - mx);
    float inv = 1.0f / s;
    for (int i = 0; i < n; ++i) dst[i] = expf(src[i] - mx) * inv;
}

// ---------------------------------------------------------------------------
// Conv v5. Planar [48][C][H][W] log field, fused virtual pre-pad.
// Block = 256 threads (4 waves). Wave w: co-group (w % NG), y-subtile (w / NG).
// Lane: row = l>>3 (8 rows), xq = (l&7)*4 (32 cols, 4 px/thread).
// Weights in LDS, co-major: wl[((ci*K+kh)*K+kw)*CO + co] -> float4 broadcast.
// ---------------------------------------------------------------------------
template<int CI, int CO, int K>
__global__ __launch_bounds__(256)
void conv_tile(const float* __restrict__ in, float* __restrict__ out,
               const float* __restrict__ wn, int Hin, int Win, int pad) {
    constexpr int COT = (CO < 4) ? CO : 4;
    constexpr int NG = CO / COT;        // co groups (1,2,4)
    constexpr int YS = 4 / NG;          // y subtiles per block
    constexpr int BH = 8 * YS;          // block tile height
    constexpr int BW = 32;              // block tile width
    constexpr int CC = (CI > 8) ? 8 : CI;
    constexpr int THI = BH + K - 1;
    constexpr int TWI = BW + K - 1;
    constexpr int ROWW = (TWI + 3) & ~3;
    constexpr int NW = CI * K * K * CO;

    __shared__ float wl[NW];
    __shared__ float itile[CC][THI][ROWW];

    const int tid = threadIdx.x;
    const int wv = __builtin_amdgcn_readfirstlane(tid >> 6);
    const int cog = wv % NG;            // wave-uniform co group
    const int ys = wv / NG;             // wave-uniform y subtile
    const int l = tid & 63;
    const int row = l >> 3;             // 0..7
    const int xq = (l & 7) * 4;         // 0,4,...,28

    const int nb = blockIdx.z;
    const int gy0 = blockIdx.y * BH;
    const int gx0 = blockIdx.x * BW;
    const int Ho = Hin + pad - K + 1;
    const int Wo = Win + pad - K + 1;

    // stage softmaxed weights once: wl[idx*CO + co], idx=(ci*K+kh)*K+kw
    for (int i = tid; i < NW; i += 256) {
        int co = i % CO;
        int idx = i / CO;
        int kw = idx % K; int t = idx / K;
        int kh = t % K; int ci = t / K;
        wl[i] = wn[((co * CI + ci) * K + kh) * K + kw];
    }

    float acc[COT][4];
#pragma unroll
    for (int c2 = 0; c2 < COT; ++c2)
#pragma unroll
        for (int p = 0; p < 4; ++p) acc[c2][p] = 0.f;

    const int srow = ys * 8 + row;      // row within block tile

    for (int c0 = 0; c0 < CI; c0 += CC) {
        __syncthreads();
#pragma unroll
        for (int cc = 0; cc < CC; ++cc) {
            const float* ibase = in + ((size_t)(nb * CI + c0 + cc) * Hin) * Win;
            for (int idx = tid; idx < THI * TWI; idx += 256) {
                int r = idx / TWI;
                int c = idx - r * TWI;
                int gy = gy0 + r, gx = gx0 + c;
                float v = 0.f;
                if (gy >= pad && gy < Hin && gx >= pad && gx < Win)
                    v = ibase[(size_t)(gy - pad) * Win + (gx - pad)];
                itile[cc][r][c] = v;
            }
        }
        __syncthreads();
#pragma unroll
        for (int cc = 0; cc < CC; ++cc) {
            const int ci = c0 + cc;
#pragma unroll
            for (int kh = 0; kh < K; ++kh) {
                const float* rp = &itile[cc][srow + kh][xq];
                float4 a = *(const float4*)rp;
                float rv[4 + K - 1];
                rv[0] = a.x; rv[1] = a.y; rv[2] = a.z; rv[3] = a.w;
                if constexpr (K >= 2) rv[4] = rp[4];
                if constexpr (K >= 3) rv[5] = rp[5];
#pragma unroll
                for (int kw = 0; kw < K; ++kw) {
                    const float* wp = &wl[((ci * K + kh) * K + kw) * CO + cog * COT];
                    if constexpr (COT == 4) {
                        float4 wq = *(const float4*)wp;   // broadcast ds_read_b128
                        float wqa[4] = {wq.x, wq.y, wq.z, wq.w};
#pragma unroll
                        for (int c2 = 0; c2 < 4; ++c2)
#pragma unroll
                            for (int p = 0; p < 4; ++p)
                                acc[c2][p] = fmaf(rv[p + kw], wqa[c2], acc[c2][p]);
                    } else {
                        float w0 = wp[0];
#pragma unroll
                        for (int p = 0; p < 4; ++p)
                            acc[0][p] = fmaf(rv[p + kw], w0, acc[0][p]);
                    }
                }
            }
        }
    }

    const int oy = gy0 + srow;
    const int ox0 = gx0 + xq;
    if (oy < Ho) {
#pragma unroll
        for (int c2 = 0; c2 < COT; ++c2) {
            float* ob = out + ((size_t)(nb * CO + cog * COT + c2) * Ho + oy) * Wo + ox0;
#pragma unroll
            for (int p = 0; p < 4; ++p)
                if (ox0 + p < Wo) ob[p] = acc[c2][p];
        }
    }
}

extern "C" void kernel_launch(void* const* d_in, const int* in_sizes, int n_in,
                              void* d_out, int out_size, void* d_ws, size_t ws_size,
                              hipStream_t stream) {
    const float* x = (const float*)d_in[0];
    float* out = (float*)d_out;
    float* ws = (float*)d_ws;

    static const int CiA[10]  = {1, 4, 8, 16, 16, 8, 16, 16, 8, 4};
    static const int CoA[10]  = {4, 8, 16, 16, 8, 16, 16, 8, 4, 1};
    static const int KA[10]   = {3, 3, 3, 2, 2, 2, 2, 3, 3, 3};
    static const int PREPAD[10] = {0, 0, 0, 0, 0, 2, 2, 4, 4, 4};

    int wnoff[11]; wnoff[0] = 0;
    for (int l = 0; l < 10; ++l)
        wnoff[l + 1] = wnoff[l] + CoA[l] * CiA[l] * KA[l] * KA[l];

    float* wn = ws;                       // softmaxed weights (< 8192 floats)
    const size_t BUF = 6900000;
    float* bufA = ws + 8192;
    float* bufB = bufA + BUF;

    WP wp;
    for (int l = 0; l < 10; ++l) {
        wp.src[l] = (const float*)d_in[1 + l];
        wp.dst[l] = wn + wnoff[l];
        wp.Co[l] = CoA[l];
        wp.n[l] = CiA[l] * KA[l] * KA[l];
    }
    softmax_all<<<10, 64, 0, stream>>>(wp);

    const int NB = 48;                    // 6 comps * 8 batch
    const int NMAT = 8 * 96 * 96;
    logm_k<<<(NMAT + 255) / 256, 256, 0, stream>>>(x, bufA, NMAT);

    float* cur = bufA;
    float* nxt = bufB;
    int H = 96, W = 96;                   // stored dims of cur

#define RUN_LAYER(L, CI_, CO_, K_)                                          \
    {                                                                       \
        int pad = PREPAD[L];                                                \
        int Ho = H + pad - K_ + 1, Wo = W + pad - K_ + 1;                   \
        constexpr int COT_ = (CO_ < 4) ? CO_ : 4;                           \
        constexpr int NG_ = CO_ / COT_;                                     \
        constexpr int BH_ = 8 * (4 / NG_);                                  \
        dim3 grd((Wo + 31) / 32, (Ho + BH_ - 1) / BH_, NB);                 \
        conv_tile<CI_, CO_, K_><<<grd, 256, 0, stream>>>(                   \
            cur, nxt, wn + wnoff[L], H, W, pad);                            \
        { float* t = cur; cur = nxt; nxt = t; }                             \
        H = Ho; W = Wo;                                                     \
    }

    RUN_LAYER(0, 1, 4, 3)
    RUN_LAYER(1, 4, 8, 3)
    RUN_LAYER(2, 8, 16, 3)
    RUN_LAYER(3, 16, 16, 2)
    RUN_LAYER(4, 16, 8, 2)
    RUN_LAYER(5, 8, 16, 2)
    RUN_LAYER(6, 16, 16, 2)
    RUN_LAYER(7, 16, 8, 3)
    RUN_LAYER(8, 8, 4, 3)
    RUN_LAYER(9, 4, 1, 3)
#undef RUN_LAYER

    expm_k<<<(NMAT + 255) / 256, 256, 0, stream>>>(cur, out, NMAT);
}

// Round 6
// 315.900 us; speedup vs baseline: 1.3469x; 1.3469x over previous
//
#include <hip/hip_runtime.h>
#include <math.h>

// ---------------------------------------------------------------------------
// ManifoldNet SPD network, fused in log-domain.
// logm(x) once -> 10 convs (zero-pad fused into staging) on the 6 unique
// components of the symmetric log field (treated as batch) -> expm once.
// Conv v6: v5 structure (LDS weights broadcast, wave co/y split, P=4) with
// register pressure capped: unroll-1 on channel loop + launch_bounds(256,4).
// ---------------------------------------------------------------------------

#define DEVFN __device__ __forceinline__

DEVFN void jrot(float A[3][3], float V[3][3], int p, int q) {
    float apq = A[p][q];
    if (fabsf(apq) < 1e-30f) return;
    float app = A[p][p], aqq = A[q][q];
    float tau = (aqq - app) / (2.0f * apq);
    float t = copysignf(1.0f, tau) / (fabsf(tau) + sqrtf(1.0f + tau * tau));
    float c = rsqrtf(1.0f + t * t);
    float s = t * c;
    int r = 3 - p - q;
    float arp = A[r][p], arq = A[r][q];
    A[p][p] = app - t * apq;
    A[q][q] = aqq + t * apq;
    A[p][q] = 0.0f; A[q][p] = 0.0f;
    A[r][p] = c * arp - s * arq; A[p][r] = A[r][p];
    A[r][q] = s * arp + c * arq; A[q][r] = A[r][q];
#pragma unroll
    for (int i = 0; i < 3; ++i) {
        float vip = V[i][p], viq = V[i][q];
        V[i][p] = c * vip - s * viq;
        V[i][q] = s * vip + c * viq;
    }
}

DEVFN void eigh3(float A[3][3], float V[3][3]) {
    V[0][0] = 1.f; V[0][1] = 0.f; V[0][2] = 0.f;
    V[1][0] = 0.f; V[1][1] = 1.f; V[1][2] = 0.f;
    V[2][0] = 0.f; V[2][1] = 0.f; V[2][2] = 1.f;
#pragma unroll
    for (int s = 0; s < 6; ++s) {
        jrot(A, V, 0, 1);
        jrot(A, V, 0, 2);
        jrot(A, V, 1, 2);
    }
}

// x: [n,3,3] SPD (f32). out: planar [6][n], comps (00,01,02,11,12,22).
__global__ void logm_k(const float* __restrict__ x, float* __restrict__ out, int n) {
    int i = blockIdx.x * blockDim.x + threadIdx.x;
    if (i >= n) return;
    const float* m = x + (size_t)i * 9;
    float a01 = 0.5f * (m[1] + m[3]);
    float a02 = 0.5f * (m[2] + m[6]);
    float a12 = 0.5f * (m[5] + m[7]);
    float A[3][3] = {{m[0], a01, a02}, {a01, m[4], a12}, {a02, a12, m[8]}};
    float V[3][3];
    eigh3(A, V);
    float d0 = logf(fmaxf(A[0][0], 1e-30f));
    float d1 = logf(fmaxf(A[1][1], 1e-30f));
    float d2 = logf(fmaxf(A[2][2], 1e-30f));
    float L00 = V[0][0]*d0*V[0][0] + V[0][1]*d1*V[0][1] + V[0][2]*d2*V[0][2];
    float L01 = V[0][0]*d0*V[1][0] + V[0][1]*d1*V[1][1] + V[0][2]*d2*V[1][2];
    float L02 = V[0][0]*d0*V[2][0] + V[0][1]*d1*V[2][1] + V[0][2]*d2*V[2][2];
    float L11 = V[1][0]*d0*V[1][0] + V[1][1]*d1*V[1][1] + V[1][2]*d2*V[1][2];
    float L12 = V[1][0]*d0*V[2][0] + V[1][1]*d1*V[2][1] + V[1][2]*d2*V[2][2];
    float L22 = V[2][0]*d0*V[2][0] + V[2][1]*d1*V[2][1] + V[2][2]*d2*V[2][2];
    out[0 * (size_t)n + i] = L00;
    out[1 * (size_t)n + i] = L01;
    out[2 * (size_t)n + i] = L02;
    out[3 * (size_t)n + i] = L11;
    out[4 * (size_t)n + i] = L12;
    out[5 * (size_t)n + i] = L22;
}

__global__ void expm_k(const float* __restrict__ Lp, float* __restrict__ out, int n) {
    int i = blockIdx.x * blockDim.x + threadIdx.x;
    if (i >= n) return;
    float a00 = Lp[0 * (size_t)n + i];
    float a01 = Lp[1 * (size_t)n + i];
    float a02 = Lp[2 * (size_t)n + i];
    float a11 = Lp[3 * (size_t)n + i];
    float a12 = Lp[4 * (size_t)n + i];
    float a22 = Lp[5 * (size_t)n + i];
    float A[3][3] = {{a00, a01, a02}, {a01, a11, a12}, {a02, a12, a22}};
    float V[3][3];
    eigh3(A, V);
    float e0 = expf(A[0][0]);
    float e1 = expf(A[1][1]);
    float e2 = expf(A[2][2]);
    float m00 = V[0][0]*e0*V[0][0] + V[0][1]*e1*V[0][1] + V[0][2]*e2*V[0][2];
    float m01 = V[0][0]*e0*V[1][0] + V[0][1]*e1*V[1][1] + V[0][2]*e2*V[1][2];
    float m02 = V[0][0]*e0*V[2][0] + V[0][1]*e1*V[2][1] + V[0][2]*e2*V[2][2];
    float m11 = V[1][0]*e0*V[1][0] + V[1][1]*e1*V[1][1] + V[1][2]*e2*V[1][2];
    float m12 = V[1][0]*e0*V[2][0] + V[1][1]*e1*V[2][1] + V[1][2]*e2*V[2][2];
    float m22 = V[2][0]*e0*V[2][0] + V[2][1]*e1*V[2][1] + V[2][2]*e2*V[2][2];
    float* o = out + (size_t)i * 9;
    o[0] = m00; o[1] = m01; o[2] = m02;
    o[3] = m01; o[4] = m11; o[5] = m12;
    o[6] = m02; o[7] = m12; o[8] = m22;
}

// One kernel for all 10 layer softmaxes: block l = layer l, thread co.
struct WP {
    const float* src[10];
    float* dst[10];
    int Co[10];
    int n[10];
};
__global__ void softmax_all(WP wp) {
    int l = blockIdx.x;
    int co = threadIdx.x;
    if (co >= wp.Co[l]) return;
    int n = wp.n[l];
    const float* src = wp.src[l] + (size_t)co * n;
    float* dst = wp.dst[l] + (size_t)co * n;
    float mx = -1e30f;
    for (int i = 0; i < n; ++i) mx = fmaxf(mx, src[i]);
    float s = 0.f;
    for (int i = 0; i < n; ++i) s += expf(src[i] - mx);
    float inv = 1.0f / s;
    for (int i = 0; i < n; ++i) dst[i] = expf(src[i] - mx) * inv;
}

// ---------------------------------------------------------------------------
// Conv v6. Planar [48][C][H][W] log field, fused virtual pre-pad.
// Block = 256 threads (4 waves). Wave w: co-group (w % NG), y-subtile (w / NG).
// Lane: row = l>>3 (8 rows), xq = (l&7)*4 (32 cols, 4 px/thread).
// Weights in LDS, co-major: wl[((ci*K+kh)*K+kw)*CO + co] -> float4 broadcast.
// Channel loop NOT unrolled (register pressure control).
// ---------------------------------------------------------------------------
template<int CI, int CO, int K>
__global__ __launch_bounds__(256, 4)
void conv_tile(const float* __restrict__ in, float* __restrict__ out,
               const float* __restrict__ wn, int Hin, int Win, int pad) {
    constexpr int COT = (CO < 4) ? CO : 4;
    constexpr int NG = CO / COT;        // co groups (1,2,4)
    constexpr int YS = 4 / NG;          // y subtiles per block
    constexpr int BH = 8 * YS;          // block tile height
    constexpr int BW = 32;              // block tile width
    constexpr int CC = (CI > 8) ? 8 : CI;
    constexpr int THI = BH + K - 1;
    constexpr int TWI = BW + K - 1;
    constexpr int ROWW = (TWI + 3) & ~3;
    constexpr int NW = CI * K * K * CO;

    __shared__ float wl[NW];
    __shared__ float itile[CC][THI][ROWW];

    const int tid = threadIdx.x;
    const int wv = __builtin_amdgcn_readfirstlane(tid >> 6);
    const int cog = wv % NG;            // wave-uniform co group
    const int ys = wv / NG;             // wave-uniform y subtile
    const int l = tid & 63;
    const int row = l >> 3;             // 0..7
    const int xq = (l & 7) * 4;         // 0,4,...,28

    const int nb = blockIdx.z;
    const int gy0 = blockIdx.y * BH;
    const int gx0 = blockIdx.x * BW;
    const int Ho = Hin + pad - K + 1;
    const int Wo = Win + pad - K + 1;

    // stage softmaxed weights once: wl[idx*CO + co], idx=(ci*K+kh)*K+kw
    for (int i = tid; i < NW; i += 256) {
        int co = i % CO;
        int idx = i / CO;
        int kw = idx % K; int t = idx / K;
        int kh = t % K; int ci = t / K;
        wl[i] = wn[((co * CI + ci) * K + kh) * K + kw];
    }

    float acc[COT][4];
#pragma unroll
    for (int c2 = 0; c2 < COT; ++c2)
#pragma unroll
        for (int p = 0; p < 4; ++p) acc[c2][p] = 0.f;

    const int srow = ys * 8 + row;      // row within block tile

    for (int c0 = 0; c0 < CI; c0 += CC) {
        __syncthreads();
#pragma unroll 1
        for (int cc = 0; cc < CC; ++cc) {
            const float* ibase = in + ((size_t)(nb * CI + c0 + cc) * Hin) * Win;
            for (int idx = tid; idx < THI * TWI; idx += 256) {
                int r = idx / TWI;
                int c = idx - r * TWI;
                int gy = gy0 + r, gx = gx0 + c;
                float v = 0.f;
                if (gy >= pad && gy < Hin && gx >= pad && gx < Win)
                    v = ibase[(size_t)(gy - pad) * Win + (gx - pad)];
                itile[cc][r][c] = v;
            }
        }
        __syncthreads();
#pragma unroll 1
        for (int cc = 0; cc < CC; ++cc) {
            const int ci = c0 + cc;
#pragma unroll
            for (int kh = 0; kh < K; ++kh) {
                const float* rp = &itile[cc][srow + kh][xq];
                float4 a = *(const float4*)rp;
                float rv[4 + K - 1];
                rv[0] = a.x; rv[1] = a.y; rv[2] = a.z; rv[3] = a.w;
                if constexpr (K >= 2) rv[4] = rp[4];
                if constexpr (K >= 3) rv[5] = rp[5];
#pragma unroll
                for (int kw = 0; kw < K; ++kw) {
                    const float* wp = &wl[((ci * K + kh) * K + kw) * CO + cog * COT];
                    if constexpr (COT == 4) {
                        float4 wq = *(const float4*)wp;   // broadcast ds_read_b128
                        float wqa[4] = {wq.x, wq.y, wq.z, wq.w};
#pragma unroll
                        for (int c2 = 0; c2 < 4; ++c2)
#pragma unroll
                            for (int p = 0; p < 4; ++p)
                                acc[c2][p] = fmaf(rv[p + kw], wqa[c2], acc[c2][p]);
                    } else {
                        float w0 = wp[0];
#pragma unroll
                        for (int p = 0; p < 4; ++p)
                            acc[0][p] = fmaf(rv[p + kw], w0, acc[0][p]);
                    }
                }
            }
        }
    }

    const int oy = gy0 + srow;
    const int ox0 = gx0 + xq;
    if (oy < Ho) {
#pragma unroll
        for (int c2 = 0; c2 < COT; ++c2) {
            float* ob = out + ((size_t)(nb * CO + cog * COT + c2) * Ho + oy) * Wo + ox0;
#pragma unroll
            for (int p = 0; p < 4; ++p)
                if (ox0 + p < Wo) ob[p] = acc[c2][p];
        }
    }
}

extern "C" void kernel_launch(void* const* d_in, const int* in_sizes, int n_in,
                              void* d_out, int out_size, void* d_ws, size_t ws_size,
                              hipStream_t stream) {
    const float* x = (const float*)d_in[0];
    float* out = (float*)d_out;
    float* ws = (float*)d_ws;

    static const int CiA[10]  = {1, 4, 8, 16, 16, 8, 16, 16, 8, 4};
    static const int CoA[10]  = {4, 8, 16, 16, 8, 16, 16, 8, 4, 1};
    static const int KA[10]   = {3, 3, 3, 2, 2, 2, 2, 3, 3, 3};
    static const int PREPAD[10] = {0, 0, 0, 0, 0, 2, 2, 4, 4, 4};

    int wnoff[11]; wnoff[0] = 0;
    for (int l = 0; l < 10; ++l)
        wnoff[l + 1] = wnoff[l] + CoA[l] * CiA[l] * KA[l] * KA[l];

    float* wn = ws;                       // softmaxed weights (< 8192 floats)
    const size_t BUF = 6900000;
    float* bufA = ws + 8192;
    float* bufB = bufA + BUF;

    WP wp;
    for (int l = 0; l < 10; ++l) {
        wp.src[l] = (const float*)d_in[1 + l];
        wp.dst[l] = wn + wnoff[l];
        wp.Co[l] = CoA[l];
        wp.n[l] = CiA[l] * KA[l] * KA[l];
    }
    softmax_all<<<10, 64, 0, stream>>>(wp);

    const int NB = 48;                    // 6 comps * 8 batch
    const int NMAT = 8 * 96 * 96;
    logm_k<<<(NMAT + 255) / 256, 256, 0, stream>>>(x, bufA, NMAT);

    float* cur = bufA;
    float* nxt = bufB;
    int H = 96, W = 96;                   // stored dims of cur

#define RUN_LAYER(L, CI_, CO_, K_)                                          \
    {                                                                       \
        int pad = PREPAD[L];                                                \
        int Ho = H + pad - K_ + 1, Wo = W + pad - K_ + 1;                   \
        constexpr int COT_ = (CO_ < 4) ? CO_ : 4;                           \
        constexpr int NG_ = CO_ / COT_;                                     \
        constexpr int BH_ = 8 * (4 / NG_);                                  \
        dim3 grd((Wo + 31) / 32, (Ho + BH_ - 1) / BH_, NB);                 \
        conv_tile<CI_, CO_, K_><<<grd, 256, 0, stream>>>(                   \
            cur, nxt, wn + wnoff[L], H, W, pad);                            \
        { float* t = cur; cur = nxt; nxt = t; }                             \
        H = Ho; W = Wo;                                                     \
    }

    RUN_LAYER(0, 1, 4, 3)
    RUN_LAYER(1, 4, 8, 3)
    RUN_LAYER(2, 8, 16, 3)
    RUN_LAYER(3, 16, 16, 2)
    RUN_LAYER(4, 16, 8, 2)
    RUN_LAYER(5, 8, 16, 2)
    RUN_LAYER(6, 16, 16, 2)
    RUN_LAYER(7, 16, 8, 3)
    RUN_LAYER(8, 8, 4, 3)
    RUN_LAYER(9, 4, 1, 3)
#undef RUN_LAYER

    expm_k<<<(NMAT + 255) / 256, 256, 0, stream>>>(cur, out, NMAT);
}

// Round 7
// 269.169 us; speedup vs baseline: 1.5808x; 1.1736x over previous
//
#include <hip/hip_runtime.h>
#include <math.h>

// ---------------------------------------------------------------------------
// ManifoldNet SPD network, fused in log-domain.
// prep_k: wave-parallel softmax of all 10 weight tensors (blocks 0..9) +
//         logm of input field (blocks 10..). Then 10 convs (zero-pad fused
//         into staging) on the 6 unique components of the symmetric log
//         field -> expm once.
// Conv v6: LDS weights broadcast, wave co/y split, P=4 px/thread,
// register pressure capped (unroll 1 + launch_bounds(256,4)).
// ---------------------------------------------------------------------------

#define DEVFN __device__ __forceinline__

DEVFN void jrot(float A[3][3], float V[3][3], int p, int q) {
    float apq = A[p][q];
    if (fabsf(apq) < 1e-30f) return;
    float app = A[p][p], aqq = A[q][q];
    float tau = (aqq - app) / (2.0f * apq);
    float t = copysignf(1.0f, tau) / (fabsf(tau) + sqrtf(1.0f + tau * tau));
    float c = rsqrtf(1.0f + t * t);
    float s = t * c;
    int r = 3 - p - q;
    float arp = A[r][p], arq = A[r][q];
    A[p][p] = app - t * apq;
    A[q][q] = aqq + t * apq;
    A[p][q] = 0.0f; A[q][p] = 0.0f;
    A[r][p] = c * arp - s * arq; A[p][r] = A[r][p];
    A[r][q] = s * arp + c * arq; A[q][r] = A[r][q];
#pragma unroll
    for (int i = 0; i < 3; ++i) {
        float vip = V[i][p], viq = V[i][q];
        V[i][p] = c * vip - s * viq;
        V[i][q] = s * vip + c * viq;
    }
}

DEVFN void eigh3(float A[3][3], float V[3][3]) {
    V[0][0] = 1.f; V[0][1] = 0.f; V[0][2] = 0.f;
    V[1][0] = 0.f; V[1][1] = 1.f; V[1][2] = 0.f;
    V[2][0] = 0.f; V[2][1] = 0.f; V[2][2] = 1.f;
#pragma unroll
    for (int s = 0; s < 6; ++s) {
        jrot(A, V, 0, 1);
        jrot(A, V, 0, 2);
        jrot(A, V, 1, 2);
    }
}

struct WP {
    const float* src[10];
    float* dst[10];
    int Co[10];
    int n[10];
};

// blocks 0..9: wave-parallel softmax for layer blockIdx.x.
// blocks 10..: logm of matrices. x: [n,3,3] SPD -> out planar [6][n].
__global__ __launch_bounds__(256)
void prep_k(WP wp, const float* __restrict__ x, float* __restrict__ out, int n) {
    if (blockIdx.x < 10) {
        const int l = blockIdx.x;
        const int wv = threadIdx.x >> 6;
        const int lane = threadIdx.x & 63;
        const int Co = wp.Co[l], nn = wp.n[l];
        for (int co = wv; co < Co; co += 4) {
            const float* src = wp.src[l] + (size_t)co * nn;
            float v0 = (lane < nn) ? src[lane] : -1e30f;
            float v1 = (lane + 64 < nn) ? src[lane + 64] : -1e30f;
            float v2 = (lane + 128 < nn) ? src[lane + 128] : -1e30f;
            float mx = fmaxf(fmaxf(v0, v1), v2);
#pragma unroll
            for (int off = 32; off; off >>= 1)
                mx = fmaxf(mx, __shfl_xor(mx, off));
            float e0 = (lane < nn) ? expf(v0 - mx) : 0.f;
            float e1 = (lane + 64 < nn) ? expf(v1 - mx) : 0.f;
            float e2 = (lane + 128 < nn) ? expf(v2 - mx) : 0.f;
            float s = e0 + e1 + e2;
#pragma unroll
            for (int off = 32; off; off >>= 1)
                s += __shfl_xor(s, off);
            float inv = 1.0f / s;
            float* dst = wp.dst[l] + (size_t)co * nn;
            if (lane < nn) dst[lane] = e0 * inv;
            if (lane + 64 < nn) dst[lane + 64] = e1 * inv;
            if (lane + 128 < nn) dst[lane + 128] = e2 * inv;
        }
        return;
    }
    int i = (blockIdx.x - 10) * 256 + threadIdx.x;
    if (i >= n) return;
    const float* m = x + (size_t)i * 9;
    float a01 = 0.5f * (m[1] + m[3]);
    float a02 = 0.5f * (m[2] + m[6]);
    float a12 = 0.5f * (m[5] + m[7]);
    float A[3][3] = {{m[0], a01, a02}, {a01, m[4], a12}, {a02, a12, m[8]}};
    float V[3][3];
    eigh3(A, V);
    float d0 = logf(fmaxf(A[0][0], 1e-30f));
    float d1 = logf(fmaxf(A[1][1], 1e-30f));
    float d2 = logf(fmaxf(A[2][2], 1e-30f));
    float L00 = V[0][0]*d0*V[0][0] + V[0][1]*d1*V[0][1] + V[0][2]*d2*V[0][2];
    float L01 = V[0][0]*d0*V[1][0] + V[0][1]*d1*V[1][1] + V[0][2]*d2*V[1][2];
    float L02 = V[0][0]*d0*V[2][0] + V[0][1]*d1*V[2][1] + V[0][2]*d2*V[2][2];
    float L11 = V[1][0]*d0*V[1][0] + V[1][1]*d1*V[1][1] + V[1][2]*d2*V[1][2];
    float L12 = V[1][0]*d0*V[2][0] + V[1][1]*d1*V[2][1] + V[1][2]*d2*V[2][2];
    float L22 = V[2][0]*d0*V[2][0] + V[2][1]*d1*V[2][1] + V[2][2]*d2*V[2][2];
    out[0 * (size_t)n + i] = L00;
    out[1 * (size_t)n + i] = L01;
    out[2 * (size_t)n + i] = L02;
    out[3 * (size_t)n + i] = L11;
    out[4 * (size_t)n + i] = L12;
    out[5 * (size_t)n + i] = L22;
}

__global__ void expm_k(const float* __restrict__ Lp, float* __restrict__ out, int n) {
    int i = blockIdx.x * blockDim.x + threadIdx.x;
    if (i >= n) return;
    float a00 = Lp[0 * (size_t)n + i];
    float a01 = Lp[1 * (size_t)n + i];
    float a02 = Lp[2 * (size_t)n + i];
    float a11 = Lp[3 * (size_t)n + i];
    float a12 = Lp[4 * (size_t)n + i];
    float a22 = Lp[5 * (size_t)n + i];
    float A[3][3] = {{a00, a01, a02}, {a01, a11, a12}, {a02, a12, a22}};
    float V[3][3];
    eigh3(A, V);
    float e0 = expf(A[0][0]);
    float e1 = expf(A[1][1]);
    float e2 = expf(A[2][2]);
    float m00 = V[0][0]*e0*V[0][0] + V[0][1]*e1*V[0][1] + V[0][2]*e2*V[0][2];
    float m01 = V[0][0]*e0*V[1][0] + V[0][1]*e1*V[1][1] + V[0][2]*e2*V[1][2];
    float m02 = V[0][0]*e0*V[2][0] + V[0][1]*e1*V[2][1] + V[0][2]*e2*V[2][2];
    float m11 = V[1][0]*e0*V[1][0] + V[1][1]*e1*V[1][1] + V[1][2]*e2*V[1][2];
    float m12 = V[1][0]*e0*V[2][0] + V[1][1]*e1*V[2][1] + V[1][2]*e2*V[2][2];
    float m22 = V[2][0]*e0*V[2][0] + V[2][1]*e1*V[2][1] + V[2][2]*e2*V[2][2];
    float* o = out + (size_t)i * 9;
    o[0] = m00; o[1] = m01; o[2] = m02;
    o[3] = m01; o[4] = m11; o[5] = m12;
    o[6] = m02; o[7] = m12; o[8] = m22;
}

// ---------------------------------------------------------------------------
// Conv v6. Planar [48][C][H][W] log field, fused virtual pre-pad.
// Block = 256 threads (4 waves). Wave w: co-group (w % NG), y-subtile (w / NG).
// Lane: row = l>>3 (8 rows), xq = (l&7)*4 (32 cols, 4 px/thread).
// Weights in LDS, co-major: wl[((ci*K+kh)*K+kw)*CO + co] -> float4 broadcast.
// Channel loop NOT unrolled (register pressure control).
// ---------------------------------------------------------------------------
template<int CI, int CO, int K>
__global__ __launch_bounds__(256, 4)
void conv_tile(const float* __restrict__ in, float* __restrict__ out,
               const float* __restrict__ wn, int Hin, int Win, int pad) {
    constexpr int COT = (CO < 4) ? CO : 4;
    constexpr int NG = CO / COT;        // co groups (1,2,4)
    constexpr int YS = 4 / NG;          // y subtiles per block
    constexpr int BH = 8 * YS;          // block tile height
    constexpr int BW = 32;              // block tile width
    constexpr int CC = (CI > 8) ? 8 : CI;
    constexpr int THI = BH + K - 1;
    constexpr int TWI = BW + K - 1;
    constexpr int ROWW = (TWI + 3) & ~3;
    constexpr int NW = CI * K * K * CO;

    __shared__ float wl[NW];
    __shared__ float itile[CC][THI][ROWW];

    const int tid = threadIdx.x;
    const int wv = __builtin_amdgcn_readfirstlane(tid >> 6);
    const int cog = wv % NG;            // wave-uniform co group
    const int ys = wv / NG;             // wave-uniform y subtile
    const int l = tid & 63;
    const int row = l >> 3;             // 0..7
    const int xq = (l & 7) * 4;         // 0,4,...,28

    const int nb = blockIdx.z;
    const int gy0 = blockIdx.y * BH;
    const int gx0 = blockIdx.x * BW;
    const int Ho = Hin + pad - K + 1;
    const int Wo = Win + pad - K + 1;

    // stage softmaxed weights once: wl[idx*CO + co], idx=(ci*K+kh)*K+kw
    for (int i = tid; i < NW; i += 256) {
        int co = i % CO;
        int idx = i / CO;
        int kw = idx % K; int t = idx / K;
        int kh = t % K; int ci = t / K;
        wl[i] = wn[((co * CI + ci) * K + kh) * K + kw];
    }

    float acc[COT][4];
#pragma unroll
    for (int c2 = 0; c2 < COT; ++c2)
#pragma unroll
        for (int p = 0; p < 4; ++p) acc[c2][p] = 0.f;

    const int srow = ys * 8 + row;      // row within block tile

    for (int c0 = 0; c0 < CI; c0 += CC) {
        __syncthreads();
#pragma unroll 1
        for (int cc = 0; cc < CC; ++cc) {
            const float* ibase = in + ((size_t)(nb * CI + c0 + cc) * Hin) * Win;
            for (int idx = tid; idx < THI * TWI; idx += 256) {
                int r = idx / TWI;
                int c = idx - r * TWI;
                int gy = gy0 + r, gx = gx0 + c;
                float v = 0.f;
                if (gy >= pad && gy < Hin && gx >= pad && gx < Win)
                    v = ibase[(size_t)(gy - pad) * Win + (gx - pad)];
                itile[cc][r][c] = v;
            }
        }
        __syncthreads();
#pragma unroll 1
        for (int cc = 0; cc < CC; ++cc) {
            const int ci = c0 + cc;
#pragma unroll
            for (int kh = 0; kh < K; ++kh) {
                const float* rp = &itile[cc][srow + kh][xq];
                float4 a = *(const float4*)rp;
                float rv[4 + K - 1];
                rv[0] = a.x; rv[1] = a.y; rv[2] = a.z; rv[3] = a.w;
                if constexpr (K >= 2) rv[4] = rp[4];
                if constexpr (K >= 3) rv[5] = rp[5];
#pragma unroll
                for (int kw = 0; kw < K; ++kw) {
                    const float* wp = &wl[((ci * K + kh) * K + kw) * CO + cog * COT];
                    if constexpr (COT == 4) {
                        float4 wq = *(const float4*)wp;   // broadcast ds_read_b128
                        float wqa[4] = {wq.x, wq.y, wq.z, wq.w};
#pragma unroll
                        for (int c2 = 0; c2 < 4; ++c2)
#pragma unroll
                            for (int p = 0; p < 4; ++p)
                                acc[c2][p] = fmaf(rv[p + kw], wqa[c2], acc[c2][p]);
                    } else {
                        float w0 = wp[0];
#pragma unroll
                        for (int p = 0; p < 4; ++p)
                            acc[0][p] = fmaf(rv[p + kw], w0, acc[0][p]);
                    }
                }
            }
        }
    }

    const int oy = gy0 + srow;
    const int ox0 = gx0 + xq;
    if (oy < Ho) {
#pragma unroll
        for (int c2 = 0; c2 < COT; ++c2) {
            float* ob = out + ((size_t)(nb * CO + cog * COT + c2) * Ho + oy) * Wo + ox0;
#pragma unroll
            for (int p = 0; p < 4; ++p)
                if (ox0 + p < Wo) ob[p] = acc[c2][p];
        }
    }
}

extern "C" void kernel_launch(void* const* d_in, const int* in_sizes, int n_in,
                              void* d_out, int out_size, void* d_ws, size_t ws_size,
                              hipStream_t stream) {
    const float* x = (const float*)d_in[0];
    float* out = (float*)d_out;
    float* ws = (float*)d_ws;

    static const int CiA[10]  = {1, 4, 8, 16, 16, 8, 16, 16, 8, 4};
    static const int CoA[10]  = {4, 8, 16, 16, 8, 16, 16, 8, 4, 1};
    static const int KA[10]   = {3, 3, 3, 2, 2, 2, 2, 3, 3, 3};
    static const int PREPAD[10] = {0, 0, 0, 0, 0, 2, 2, 4, 4, 4};

    int wnoff[11]; wnoff[0] = 0;
    for (int l = 0; l < 10; ++l)
        wnoff[l + 1] = wnoff[l] + CoA[l] * CiA[l] * KA[l] * KA[l];

    float* wn = ws;                       // softmaxed weights (< 8192 floats)
    const size_t BUF = 6900000;
    float* bufA = ws + 8192;
    float* bufB = bufA + BUF;

    WP wp;
    for (int l = 0; l < 10; ++l) {
        wp.src[l] = (const float*)d_in[1 + l];
        wp.dst[l] = wn + wnoff[l];
        wp.Co[l] = CoA[l];
        wp.n[l] = CiA[l] * KA[l] * KA[l];
    }

    const int NB = 48;                    // 6 comps * 8 batch
    const int NMAT = 8 * 96 * 96;
    // fused: blocks 0..9 softmax, blocks 10.. logm
    prep_k<<<10 + (NMAT + 255) / 256, 256, 0, stream>>>(wp, x, bufA, NMAT);

    float* cur = bufA;
    float* nxt = bufB;
    int H = 96, W = 96;                   // stored dims of cur

#define RUN_LAYER(L, CI_, CO_, K_)                                          \
    {                                                                       \
        int pad = PREPAD[L];                                                \
        int Ho = H + pad - K_ + 1, Wo = W + pad - K_ + 1;                   \
        constexpr int COT_ = (CO_ < 4) ? CO_ : 4;                           \
        constexpr int NG_ = CO_ / COT_;                                     \
        constexpr int BH_ = 8 * (4 / NG_);                                  \
        dim3 grd((Wo + 31) / 32, (Ho + BH_ - 1) / BH_, NB);                 \
        conv_tile<CI_, CO_, K_><<<grd, 256, 0, stream>>>(                   \
            cur, nxt, wn + wnoff[L], H, W, pad);                            \
        { float* t = cur; cur = nxt; nxt = t; }                             \
        H = Ho; W = Wo;                                                     \
    }

    RUN_LAYER(0, 1, 4, 3)
    RUN_LAYER(1, 4, 8, 3)
    RUN_LAYER(2, 8, 16, 3)
    RUN_LAYER(3, 16, 16, 2)
    RUN_LAYER(4, 16, 8, 2)
    RUN_LAYER(5, 8, 16, 2)
    RUN_LAYER(6, 16, 16, 2)
    RUN_LAYER(7, 16, 8, 3)
    RUN_LAYER(8, 8, 4, 3)
    RUN_LAYER(9, 4, 1, 3)
#undef RUN_LAYER

    expm_k<<<(NMAT + 255) / 256, 256, 0, stream>>>(cur, out, NMAT);
}